// Round 1
// baseline (695.400 us; speedup 1.0000x reference)
//
#include <hip/hip_runtime.h>

#define N_NODES 10000
#define N_EDGES 160000

// ---------------- CSR build ----------------
__global__ void count_kernel(const int* __restrict__ ei, int* __restrict__ deg) {
    int e = blockIdx.x * blockDim.x + threadIdx.x;
    if (e < N_EDGES) {
        int dst = ei[N_EDGES + e];
        atomicAdd(&deg[dst], 1);
    }
}

__global__ void scanA_kernel(const int* __restrict__ deg, int* __restrict__ row_start,
                             int* __restrict__ chunk_tot) {
    __shared__ int s[256];
    int c = blockIdx.x, tid = threadIdx.x;
    int i = c * 256 + tid;
    int v = (i < N_NODES) ? deg[i] : 0;
    s[tid] = v;
    __syncthreads();
    for (int off = 1; off < 256; off <<= 1) {
        int t = (tid >= off) ? s[tid - off] : 0;
        __syncthreads();
        s[tid] += t;
        __syncthreads();
    }
    if (i < N_NODES) row_start[i + 1] = s[tid];
    if (tid == 255) chunk_tot[c] = s[255];
}

__global__ void scanC_kernel(int* __restrict__ row_start, const int* __restrict__ chunk_tot) {
    int c = blockIdx.x, tid = threadIdx.x;
    int off = 0;
    for (int cc = 0; cc < c; ++cc) off += chunk_tot[cc];
    int i = c * 256 + tid;
    if (i < N_NODES) row_start[i + 1] += off;
    if (c == 0 && tid == 0) row_start[0] = 0;
}

__global__ void scatter_kernel(const int* __restrict__ ei, const int* __restrict__ row_start,
                               int* __restrict__ cursor, int* __restrict__ csr_src) {
    int e = blockIdx.x * blockDim.x + threadIdx.x;
    if (e < N_EDGES) {
        int src = ei[e];
        int dst = ei[N_EDGES + e];
        int p = atomicAdd(&cursor[dst], 1);
        csr_src[row_start[dst] + p] = src;
    }
}

// ---------------- mean aggregation (gather over CSR) ----------------
__global__ __launch_bounds__(128) void aggr_kernel(const float* __restrict__ x,
                                                   const int* __restrict__ csr_src,
                                                   const int* __restrict__ row_start,
                                                   float* __restrict__ aggr) {
    int dst = blockIdx.x, tid = threadIdx.x;
    int beg = row_start[dst], end = row_start[dst + 1];
    float4 acc = make_float4(0.f, 0.f, 0.f, 0.f);
    for (int i = beg; i < end; ++i) {
        int src = csr_src[i];
        float4 v = *((const float4*)(x + (size_t)src * 512) + tid);
        acc.x += v.x; acc.y += v.y; acc.z += v.z; acc.w += v.w;
    }
    float inv = 1.0f / (float)max(end - beg, 1);
    float4 r = make_float4(acc.x * inv, acc.y * inv, acc.z * inv, acc.w * inv);
    *((float4*)(aggr + (size_t)dst * 512) + tid) = r;
}

// ---------------- generic fp32 tiled GEMM: C = act(A0@B0 [+ A1@B1] + bias) ----------------
// A: [M,K] row-major per part, B: [K,N] row-major, C: [M,N]
template <bool RELU>
__global__ __launch_bounds__(256) void gemm_kernel(const float* __restrict__ A0,
                                                   const float* __restrict__ A1,
                                                   const float* __restrict__ B0,
                                                   const float* __restrict__ B1,
                                                   const float* __restrict__ bias,
                                                   float* __restrict__ C,
                                                   int M, int K, int N) {
    const int BK = 32;
    __shared__ float As[32][68];  // [k][m], padded (+4 keeps float4 alignment, kills 8-way conflicts)
    __shared__ float Bs[32][68];  // [k][n]
    int tid = threadIdx.x;
    int rowbase = blockIdx.y * 64;
    int colbase = blockIdx.x * 64;
    float acc[4][4] = {};

    int nparts = (A1 != nullptr) ? 2 : 1;
    for (int part = 0; part < nparts; ++part) {
        const float* A = part ? A1 : A0;
        const float* B = part ? B1 : B0;
        for (int kt = 0; kt < K; kt += BK) {
            // load A tile 64x32 (transposed into LDS)
            {
                int r = tid >> 3;            // 0..31
                int c4 = (tid & 7) * 4;      // 0..28
#pragma unroll
                for (int h = 0; h < 2; ++h) {
                    int row = rowbase + r + h * 32;
                    int arow = min(row, M - 1);
                    float4 v = *(const float4*)(A + (size_t)arow * K + kt + c4);
                    As[c4 + 0][r + h * 32] = v.x;
                    As[c4 + 1][r + h * 32] = v.y;
                    As[c4 + 2][r + h * 32] = v.z;
                    As[c4 + 3][r + h * 32] = v.w;
                }
            }
            // load B tile 32x64
            {
                int kr = tid >> 4;           // 0..15
                int c4 = (tid & 15) * 4;     // 0..60
#pragma unroll
                for (int h = 0; h < 2; ++h) {
                    int k = kt + kr + h * 16;
                    int col = colbase + c4;
                    float4 v;
                    if (col + 4 <= N) {
                        v = *(const float4*)(B + (size_t)k * N + col);
                    } else {
                        v.x = (col + 0 < N) ? B[(size_t)k * N + col + 0] : 0.f;
                        v.y = (col + 1 < N) ? B[(size_t)k * N + col + 1] : 0.f;
                        v.z = (col + 2 < N) ? B[(size_t)k * N + col + 2] : 0.f;
                        v.w = (col + 3 < N) ? B[(size_t)k * N + col + 3] : 0.f;
                    }
                    *(float4*)&Bs[kr + h * 16][c4] = v;
                }
            }
            __syncthreads();
            int tm = (tid & 15) * 4;
            int tn = (tid >> 4) * 4;
#pragma unroll
            for (int kk = 0; kk < BK; ++kk) {
                float4 av = *(const float4*)&As[kk][tm];
                float4 bv = *(const float4*)&Bs[kk][tn];
                float a[4] = {av.x, av.y, av.z, av.w};
                float b[4] = {bv.x, bv.y, bv.z, bv.w};
#pragma unroll
                for (int i = 0; i < 4; ++i)
#pragma unroll
                    for (int j = 0; j < 4; ++j) acc[i][j] += a[i] * b[j];
            }
            __syncthreads();
        }
    }

    int tm = (tid & 15) * 4;
    int tn = (tid >> 4) * 4;
#pragma unroll
    for (int i = 0; i < 4; ++i) {
        int row = rowbase + tm + i;
        if (row >= M) continue;
#pragma unroll
        for (int j = 0; j < 4; ++j) {
            int col = colbase + tn + j;
            if (col >= N) continue;
            float v = acc[i][j] + bias[col];
            if (RELU) v = fmaxf(v, 0.f);
            C[(size_t)row * N + col] = v;
        }
    }
}

// ---------------- pairwise L2 on [N,3] ----------------
__global__ __launch_bounds__(256) void dist_kernel(const float* __restrict__ y,
                                                   float* __restrict__ out) {
    __shared__ float sa[192];
    __shared__ float sb[192];
    int rb = blockIdx.y * 64;
    int cb = blockIdx.x * 64;
    int tid = threadIdx.x;
    if (tid < 192) {
        int ga = rb * 3 + tid;
        sa[tid] = (ga < 3 * N_NODES) ? y[ga] : 0.f;
        int gb = cb * 3 + tid;
        sb[tid] = (gb < 3 * N_NODES) ? y[gb] : 0.f;
    }
    __syncthreads();
    int ty = tid >> 4;   // 0..15
    int tx = tid & 15;   // 0..15
    int c0 = tx * 4;
#pragma unroll
    for (int i = 0; i < 4; ++i) {
        int r = ty * 4 + i;
        int row = rb + r;
        if (row >= N_NODES) continue;
        float ax = sa[r * 3 + 0], ay = sa[r * 3 + 1], az = sa[r * 3 + 2];
        float res[4];
#pragma unroll
        for (int j = 0; j < 4; ++j) {
            int cc = c0 + j;
            float dx = ax - sb[cc * 3 + 0];
            float dy = ay - sb[cc * 3 + 1];
            float dz = az - sb[cc * 3 + 2];
            res[j] = sqrtf(dx * dx + dy * dy + dz * dz);
        }
        int col = cb + c0;
        size_t base = (size_t)row * N_NODES + col;
        if (col + 4 <= N_NODES) {
            *(float4*)(out + base) = make_float4(res[0], res[1], res[2], res[3]);
        } else {
#pragma unroll
            for (int j = 0; j < 4; ++j)
                if (col + j < N_NODES) out[base + j] = res[j];
        }
    }
}

extern "C" void kernel_launch(void* const* d_in, const int* in_sizes, int n_in,
                              void* d_out, int out_size, void* d_ws, size_t ws_size,
                              hipStream_t stream) {
    const float* x   = (const float*)d_in[0];
    const int*   ei  = (const int*)d_in[1];
    const float* W_l = (const float*)d_in[2];
    const float* b_l = (const float*)d_in[3];
    const float* W_r = (const float*)d_in[4];
    const float* Wa  = (const float*)d_in[5];
    const float* ba  = (const float*)d_in[6];
    const float* W1  = (const float*)d_in[7];
    const float* b1  = (const float*)d_in[8];
    const float* W2  = (const float*)d_in[9];
    const float* b2  = (const float*)d_in[10];
    const float* W3  = (const float*)d_in[11];
    const float* b3  = (const float*)d_in[12];

    float* out = (float*)d_out;
    // big intermediates live in d_out (fully overwritten by dist_kernel at the end)
    float* aggr = out;                 // 10000*512  = 5,120,000 f
    float* h1   = out + 5120000;       // 10000*256  = 2,560,000 f
    float* h2   = out + 7680000;       // 10000*128  = 1,280,000 f
    float* h3   = out + 8960000;       // 10000*64   =   640,000 f
    float* h4   = out + 9600000;       // 10000*32   =   320,000 f

    // small stuff in d_ws (~880 KB)
    float* y        = (float*)d_ws;            // 30,000 f
    int* deg        = (int*)d_ws + 30000;      // 10,000
    int* row_start  = (int*)d_ws + 40000;      // 10,001
    int* cursor     = (int*)d_ws + 50016;      // 10,000
    int* chunk_tot  = (int*)d_ws + 60016;      // 40
    int* csr_src    = (int*)d_ws + 60064;      // 160,000

    hipMemsetAsync(deg, 0, N_NODES * sizeof(int), stream);
    hipMemsetAsync(cursor, 0, N_NODES * sizeof(int), stream);

    count_kernel<<<(N_EDGES + 255) / 256, 256, 0, stream>>>(ei, deg);
    scanA_kernel<<<40, 256, 0, stream>>>(deg, row_start, chunk_tot);
    scanC_kernel<<<40, 256, 0, stream>>>(row_start, chunk_tot);
    scatter_kernel<<<(N_EDGES + 255) / 256, 256, 0, stream>>>(ei, row_start, cursor, csr_src);
    aggr_kernel<<<N_NODES, 128, 0, stream>>>(x, csr_src, row_start, aggr);

    dim3 b256(256);
    // h1 = relu(aggr@W_l + b_l + x@W_r)   [10000,256]
    gemm_kernel<true><<<dim3(4, 157), b256, 0, stream>>>(aggr, x, W_l, W_r, b_l, h1, N_NODES, 512, 256);
    // h2 = relu(h1@Wa + ba)               [10000,128]
    gemm_kernel<true><<<dim3(2, 157), b256, 0, stream>>>(h1, nullptr, Wa, nullptr, ba, h2, N_NODES, 256, 128);
    // h3 = relu(h2@W1 + b1)               [10000,64]
    gemm_kernel<true><<<dim3(1, 157), b256, 0, stream>>>(h2, nullptr, W1, nullptr, b1, h3, N_NODES, 128, 64);
    // h4 = relu(h3@W2 + b2)               [10000,32]
    gemm_kernel<true><<<dim3(1, 157), b256, 0, stream>>>(h3, nullptr, W2, nullptr, b2, h4, N_NODES, 64, 32);
    // y  = h4@W3 + b3                     [10000,3]
    gemm_kernel<false><<<dim3(1, 157), b256, 0, stream>>>(h4, nullptr, W3, nullptr, b3, y, N_NODES, 32, 3);

    dist_kernel<<<dim3(157, 157), b256, 0, stream>>>(y, out);
}